// Round 6
// baseline (206.692 us; speedup 1.0000x reference)
//
#include <hip/hip_runtime.h>
#include <cfloat>
#include <cmath>

#define NP 10000
#define NG 1000
#define NC 80
#define LMAX 6
#define NCH 4
#define CHSZ (NP / NCH)

// scal[]: [12] anymulti (persistent), [14] nprior, [16+t] bodyran flag
#define S_MULTI 12
#define S_NPRI  14
#define S_BODY  16
#define RI_BIG  0x3fffffff

__device__ __forceinline__ bool lexless(float av, int ai, float bv, int bi) {
    return (av < bv) || (av == bv && ai < bi);
}

// Exact sequential +1e5 inflation (reference adds 1e5 once per loop iter).
__device__ __forceinline__ float inflate(float c, int k) {
    for (int q = 0; q < k; q++) c += 100000.0f;
    return c;
}

// Per-pair cost+iou from precomputed tables. Contraction OFF everywhere the
// value feeds comparisons, so all kernels agree bit-exactly.
__device__ __forceinline__ void cost_iou(float4 p, float4 pn, float4 pi,
        float4 g, float4 cb, float4 Gn, float ga, float clsv,
        float& cc_out, float& iou_out) {
#pragma clang fp contract(off)
    float wx = fminf(p.z, g.z) - fmaxf(p.x, g.x); wx = fmaxf(wx, 0.0f);
    float wy = fminf(p.w, g.w) - fmaxf(p.y, g.y); wy = fmaxf(wy, 0.0f);
    float inter = wx * wy;
    float uni = pi.z + ga - inter;
    float iou = inter / fmaxf(uni, 1e-12f);
    float ex = fmaxf(p.z, g.z) - fminf(p.x, g.x); ex = fmaxf(ex, 0.0f);
    float ey = fmaxf(p.w, g.w) - fminf(p.y, g.y); ey = fmaxf(ey, 0.0f);
    float enc = ex * ey;
    float giou = iou - (enc - uni) / fmaxf(enc, 1e-12f);
    float l1 = ((fabsf(pn.x - Gn.x) + fabsf(pn.y - Gn.y))
                + fabsf(pn.z - Gn.z)) + fabsf(pn.w - Gn.w);
    float cc = clsv + l1 * 5.0f;
    cc = cc + (-giou * 2.0f);
    bool inb = (pi.x > g.x && pi.x < g.z && pi.y > g.y && pi.y < g.w);
    bool inc = (pi.x > cb.x && pi.x < cb.z && pi.y > cb.y && pi.y < cb.w);
    cc = cc + ((inb && inc) ? 0.0f : 100.0f);
    cc = cc + pi.w;
    cc_out = cc; iou_out = iou;
}

// ---------------------------------------------------------------------------
// Fused prep. Block ranges:
//  [0,40): init state
//  [40,197): cls table, 64 preds/block (LDS transpose, coalesced both ways)
//  [197,201): per-gt tables (cb, Gn, area)
//  [201,2701): wave-per-pred validity + per-pred tables
// ---------------------------------------------------------------------------
#define CLS_TI 64
#define PB_CLS0 40
#define PB_G0   197
#define PB_V0   201
__global__ __launch_bounds__(256) void k_prep(const float* __restrict__ logits,
        const float* __restrict__ pb, const float* __restrict__ gb,
        const int* __restrict__ imgw, const int* __restrict__ imgh,
        float* __restrict__ clsval, float4* __restrict__ pnorm,
        float4* __restrict__ pinfo, float4* __restrict__ gcb,
        float4* __restrict__ gnm, float* __restrict__ gar,
        int* rowcnt, int* rowfirst, int* rowiter, int* prior, int* priorcol,
        int* colsum, int* scal)
{
    __shared__ float sl[CLS_TI * (NC + 1)];
    int b = blockIdx.x;
    if (b < PB_CLS0) {
        int i = b * 256 + threadIdx.x;
        if (i < NP) {
            rowcnt[i] = 0; rowfirst[i] = 0x7fffffff; rowiter[i] = RI_BIG;
            prior[i] = 0; priorcol[i] = 0;
        }
        if (i < NG) colsum[i] = 0;
        if (i < 32) scal[i] = 0;
    } else if (b < PB_G0) {
        int i0 = (b - PB_CLS0) * CLS_TI;
        bool full = (i0 + CLS_TI) <= NP;
        if (full) {
            const float* src = logits + (size_t)i0 * NC;
            for (int e = threadIdx.x; e < CLS_TI * NC; e += 256) {
                int di = e / NC, c = e - di * NC;
                sl[di * (NC + 1) + c] = src[e];
            }
        } else {
            for (int e = threadIdx.x; e < CLS_TI * NC; e += 256) {
                int di = e / NC, c = e - di * NC;
                int i = i0 + di;
                sl[di * (NC + 1) + c] = (i < NP) ? logits[(size_t)i * NC + c] : 0.0f;
            }
        }
        __syncthreads();
        for (int e = threadIdx.x; e < CLS_TI * NC; e += 256) {
            int c = e >> 6, di = e & 63;
            int i = i0 + di;
            if (i >= NP) continue;
            float x = sl[di * (NC + 1) + c];
            float p = 1.0f / (1.0f + expf(-x));
            float neg = -log1pf(-(p - 1e-12f)) * 0.75f * (p * p);
            float om = 1.0f - p;
            float pos = -logf(p + 1e-12f) * 0.25f * (om * om);
            clsval[(size_t)c * NP + i] = (pos - neg) * 2.0f;   // * CLS_W
        }
    } else if (b < PB_V0) {
#pragma clang fp contract(off)
        int j = (b - PB_G0) * 256 + threadIdx.x;
        if (j < NG) {
            float fw = (float)imgw[0], fh = (float)imgh[0];
            float4 g = ((const float4*)gb)[j];
            float gcx = (g.x + g.z) * 0.5f, gcy = (g.y + g.w) * 0.5f;
            float gw = g.z - g.x, gh = g.w - g.y;
            float4 cb; cb.x = gcx - 2.5f * gw; cb.y = gcy - 2.5f * gh;
            cb.z = gcx + 2.5f * gw; cb.w = gcy + 2.5f * gh;
            gcb[j] = cb;
            float4 Gn; Gn.x = g.x / fw; Gn.y = g.y / fh; Gn.z = g.z / fw; Gn.w = g.w / fh;
            gnm[j] = Gn;
            gar[j] = (g.z - g.x) * (g.w - g.y);
        }
    } else {
#pragma clang fp contract(off)
        int wave = threadIdx.x >> 6;
        int lane = threadIdx.x & 63;
        int i = (b - PB_V0) * 4 + wave;
        if (i >= NP) return;
        float4 p = ((const float4*)pb)[i];
        float pcx = (p.x + p.z) * 0.5f, pcy = (p.y + p.w) * 0.5f;
        int vb = 0, vc = 0;
        const float4* gb4 = (const float4*)gb;
        for (int j = lane; j < NG; j += 64) {
            float4 g = gb4[j];
            vb |= (pcx > g.x && pcx < g.z && pcy > g.y && pcy < g.w) ? 1 : 0;
            float gcx = (g.x + g.z) * 0.5f, gcy = (g.y + g.w) * 0.5f;
            float gw = g.z - g.x, gh = g.w - g.y;
            vc |= (pcx > gcx - 2.5f * gw && pcx < gcx + 2.5f * gw &&
                   pcy > gcy - 2.5f * gh && pcy < gcy + 2.5f * gh) ? 1 : 0;
        }
        int any = (__any(vb) ? 1 : 0) | (__any(vc) ? 1 : 0);
        if (lane == 0) {
            float fw = (float)imgw[0], fh = (float)imgh[0];
            float4 pn; pn.x = p.x / fw; pn.y = p.y / fh; pn.z = p.z / fw; pn.w = p.w / fh;
            pnorm[i] = pn;
            float4 pi4; pi4.x = pcx; pi4.y = pcy;
            pi4.z = (p.z - p.x) * (p.w - p.y);
            pi4.w = any ? 0.0f : 10000.0f;
            pinfo[i] = pi4;
        }
    }
}

// ---------------------------------------------------------------------------
// k_cost4: block (j, chunk c) scans preds [c*2500, (c+1)*2500), produces a
// sorted 5-entry partial for min-cost (lex) and max-iou. 4000 blocks.
// ---------------------------------------------------------------------------
__global__ __launch_bounds__(256) void k_cost4(
        const float* __restrict__ pb, const float* __restrict__ gb,
        const int* __restrict__ glab, const float* __restrict__ clsval,
        const float4* __restrict__ pnorm, const float4* __restrict__ pinfo,
        const float4* __restrict__ gcb, const float4* __restrict__ gnm,
        const float* __restrict__ gar,
        float* __restrict__ pcv, int* __restrict__ pci, float* __restrict__ piv)
{
    __shared__ float s_cv[256 * 7];
    __shared__ int   s_ci[256 * 7];
    __shared__ float s_iv[256 * 7];

    int j = blockIdx.x >> 2;
    int c = blockIdx.x & 3;
    float4 g  = ((const float4*)gb)[j];
    float4 cb = gcb[j];
    float4 Gn = gnm[j];
    float  ga = gar[j];
    const float* clscol = clsval + (size_t)glab[j] * NP;
    const float4* pb4 = (const float4*)pb;

    float cv[5]; int ci[5]; float iv[5];
#pragma unroll
    for (int t = 0; t < 5; t++) { cv[t] = FLT_MAX; ci[t] = 0x7fffffff; iv[t] = -1.0f; }

    int iend = (c + 1) * CHSZ;
    for (int i = c * CHSZ + threadIdx.x; i < iend; i += 256) {
        float cc, iou;
        cost_iou(pb4[i], pnorm[i], pinfo[i], g, cb, Gn, ga, clscol[i], cc, iou);

        if (lexless(cc, i, cv[4], ci[4])) {
            cv[4] = cc; ci[4] = i;
#pragma unroll
            for (int t = 4; t > 0; t--) {
                if (lexless(cv[t], ci[t], cv[t-1], ci[t-1])) {
                    float tv = cv[t]; cv[t] = cv[t-1]; cv[t-1] = tv;
                    int tx = ci[t]; ci[t] = ci[t-1]; ci[t-1] = tx;
                }
            }
        }
        if (iou > iv[4]) {
            iv[4] = iou;
#pragma unroll
            for (int t = 4; t > 0; t--) {
                if (iv[t] > iv[t-1]) { float tv = iv[t]; iv[t] = iv[t-1]; iv[t-1] = tv; }
            }
        }
    }

    int base = threadIdx.x * 7;
#pragma unroll
    for (int t = 0; t < 5; t++) { s_cv[base+t] = cv[t]; s_ci[base+t] = ci[t]; s_iv[base+t] = iv[t]; }
    s_cv[base+5] = FLT_MAX; s_ci[base+5] = 0x7fffffff; s_iv[base+5] = -2.0f;
    __syncthreads();

    for (int w = 128; w > 0; w >>= 1) {
        if (threadIdx.x < (unsigned)w) {
            int a = threadIdx.x * 7, bb = (threadIdx.x + w) * 7;
            float ov[5]; int oi[5]; float og[5];
            int pa = a, pbp = bb;
#pragma unroll
            for (int t = 0; t < 5; t++) {
                float A = s_cv[pa], B = s_cv[pbp];
                int Ai = s_ci[pa], Bi = s_ci[pbp];
                bool tA = (A < B) || (A == B && Ai <= Bi);
                if (tA) { ov[t] = A; oi[t] = Ai; pa++; } else { ov[t] = B; oi[t] = Bi; pbp++; }
            }
            int qa = a, qb = bb;
#pragma unroll
            for (int t = 0; t < 5; t++) {
                float A = s_iv[qa], B = s_iv[qb];
                if (A >= B) { og[t] = A; qa++; } else { og[t] = B; qb++; }
            }
#pragma unroll
            for (int t = 0; t < 5; t++) { s_cv[a+t] = ov[t]; s_ci[a+t] = oi[t]; s_iv[a+t] = og[t]; }
        }
        __syncthreads();
    }

    if (threadIdx.x == 0) {
        int ob = blockIdx.x * 5;
#pragma unroll
        for (int t = 0; t < 5; t++) {
            pcv[ob + t] = s_cv[t]; pci[ob + t] = s_ci[t]; piv[ob + t] = s_iv[t];
        }
    }
}

// ---------------------------------------------------------------------------
// Merge partials: thread per gt. Exact 4-way merge of sorted 5-lists
// (lex for cost; value-desc for iou, sum order-insensitive). dk, picks,
// row atomics.
// ---------------------------------------------------------------------------
__global__ __launch_bounds__(256) void k_costmerge(
        const float* __restrict__ pcv, const int* __restrict__ pci,
        const float* __restrict__ piv,
        int* __restrict__ rowcnt, int* __restrict__ rowfirst,
        int* __restrict__ rowiter, int* __restrict__ picks,
        int* __restrict__ dkarr)
{
    int j = blockIdx.x * 256 + threadIdx.x;
    if (j >= NG) return;
    int base = j * NCH * 5;
    int hc[NCH], hi[NCH];
#pragma unroll
    for (int c = 0; c < NCH; c++) { hc[c] = 0; hi[c] = 0; }

    int besti[5];
#pragma unroll
    for (int r = 0; r < 5; r++) {
        float bv = FLT_MAX; int bi = 0x7fffffff; int bc = 0;
#pragma unroll
        for (int c = 0; c < NCH; c++) {
            if (hc[c] < 5) {
                float v = pcv[base + c * 5 + hc[c]];
                int ix  = pci[base + c * 5 + hc[c]];
                if (lexless(v, ix, bv, bi)) { bv = v; bi = ix; bc = c; }
            }
        }
        besti[r] = bi; hc[bc]++;
    }
    float iv[5];
#pragma unroll
    for (int r = 0; r < 5; r++) {
        float bv = -FLT_MAX; int bc = 0;
#pragma unroll
        for (int c = 0; c < NCH; c++) {
            if (hi[c] < 5) {
                float v = piv[base + c * 5 + hi[c]];
                if (v > bv) { bv = v; bc = c; }
            }
        }
        iv[r] = bv; hi[bc]++;
    }
    float s = (((iv[0] + iv[1]) + iv[2]) + iv[3]) + iv[4];
    int dk = (int)s;                 // astype(int32): truncation
    if (dk < 1) dk = 1;
    dkarr[j] = dk;
    for (int t = 0; t < dk; t++) {
        int r = besti[t];
        picks[j * 5 + t] = r;
        atomicAdd(&rowcnt[r], 1);
        atomicMin(&rowfirst[r], j);
        atomicMin(&rowiter[r], -1);   // initially matched
    }
}

// ---------------------------------------------------------------------------
// Prior scan: rows with >1 initial assignment -> prior list.
// ---------------------------------------------------------------------------
__global__ __launch_bounds__(256) void k_pscan(const int* __restrict__ rowcnt,
        int* __restrict__ prior, int* __restrict__ plist, int* __restrict__ scal)
{
    int i = blockIdx.x * 256 + threadIdx.x;
    if (i >= NP) return;
    if (rowcnt[i] > 1) {
        prior[i] = 1;
        int idx = atomicAdd(&scal[S_NPRI], 1);
        plist[idx] = i;
    }
}

// ---------------------------------------------------------------------------
// Fused pfix + surv. Blocks [0,2500): per prior row, cooperative argmin over
// the row's (uninflated) cost -> priorcol, contribute to colsum.
// Blocks [2500,2504): surviving single-pick rows -> colsum.
// ---------------------------------------------------------------------------
__global__ __launch_bounds__(256) void k_pfixsurv(const float* __restrict__ pb,
        const float* __restrict__ gb, const int* __restrict__ glab,
        const float* __restrict__ clsval,
        const float4* __restrict__ pnorm, const float4* __restrict__ pinfo,
        const float4* __restrict__ gcb, const float4* __restrict__ gnm,
        const float* __restrict__ gar,
        const int* __restrict__ plist, int* __restrict__ priorcol,
        int* __restrict__ colsum, const int* __restrict__ scal,
        const int* __restrict__ rowcnt, const int* __restrict__ picks,
        const int* __restrict__ dkarr)
{
    int b = blockIdx.x;
    if (b >= 2500) {
        int j = (b - 2500) * 256 + threadIdx.x;
        if (j >= NG) return;
        int c = 0;
        int dk = dkarr[j];
        for (int t = 0; t < dk; t++) if (rowcnt[picks[j * 5 + t]] == 1) c++;
        if (c) atomicAdd(&colsum[j], c);
        return;
    }
    if (b >= scal[S_NPRI]) return;
    int row = plist[b];
    float4 p = ((const float4*)pb)[row];
    float4 pn = pnorm[row];
    float4 pi4 = pinfo[row];

    __shared__ float rv[256]; __shared__ int ri[256];
    float best = FLT_MAX; int bj = 0x7fffffff;
    for (int j = threadIdx.x; j < NG; j += 256) {
        float cc, iou;
        cost_iou(p, pn, pi4, ((const float4*)gb)[j], gcb[j], gnm[j], gar[j],
                 clsval[(size_t)glab[j] * NP + row], cc, iou);
        if (lexless(cc, j, best, bj)) { best = cc; bj = j; }
    }
    rv[threadIdx.x] = best; ri[threadIdx.x] = bj; __syncthreads();
    for (int w = 128; w > 0; w >>= 1) {
        if (threadIdx.x < (unsigned)w) {
            float ov = rv[threadIdx.x + w]; int oi = ri[threadIdx.x + w];
            if (lexless(ov, oi, rv[threadIdx.x], ri[threadIdx.x])) {
                rv[threadIdx.x] = ov; ri[threadIdx.x] = oi;
            }
        }
        __syncthreads();
    }
    if (threadIdx.x == 0) {
        priorcol[row] = ri[0];
        atomicAdd(&colsum[ri[0]], 1);
    }
}

// ---------------------------------------------------------------------------
// iterB: block per column; active iff colsum[j]==0. Argmin over UNINFLATED
// rows only (inflated rows strictly dominated: base <= ~10.2e3 < 1e5-50).
// rowiter < t  <=>  row matched before this iteration (inflated).
// ---------------------------------------------------------------------------
__global__ __launch_bounds__(256) void k_iterB(const float* __restrict__ pb,
        const float* __restrict__ gb, const int* __restrict__ glab,
        const float* __restrict__ clsval,
        const float4* __restrict__ pnorm, const float4* __restrict__ pinfo,
        const float4* __restrict__ gcb, const float4* __restrict__ gnm,
        const float* __restrict__ gar,
        int* __restrict__ rowiter, int* __restrict__ rowcnt,
        int* __restrict__ rowfirst, int* __restrict__ colsum,
        int* __restrict__ scal, int t)
{
    int j = blockIdx.x;
    if (colsum[j] != 0) return;
    if (threadIdx.x == 0) scal[S_BODY + t] = 1;   // body ran this iteration

    float4 g  = ((const float4*)gb)[j];
    float4 cb = gcb[j];
    float4 Gn = gnm[j];
    float  ga = gar[j];
    const float* clscol = clsval + (size_t)glab[j] * NP;
    const float4* pb4 = (const float4*)pb;

    __shared__ float rv[256]; __shared__ int ri[256];
    float best = FLT_MAX; int bi = 0x7fffffff;
    for (int i = threadIdx.x; i < NP; i += 256) {
        if (rowiter[i] < t) continue;   // inflated row: can never win
        float cc, iou;
        cost_iou(pb4[i], pnorm[i], pinfo[i], g, cb, Gn, ga, clscol[i], cc, iou);
        if (lexless(cc, i, best, bi)) { best = cc; bi = i; }
    }
    rv[threadIdx.x] = best; ri[threadIdx.x] = bi; __syncthreads();
    for (int w = 128; w > 0; w >>= 1) {
        if (threadIdx.x < (unsigned)w) {
            float ov = rv[threadIdx.x + w]; int oi = ri[threadIdx.x + w];
            if (lexless(ov, oi, rv[threadIdx.x], ri[threadIdx.x])) {
                rv[threadIdx.x] = ov; ri[threadIdx.x] = oi;
            }
        }
        __syncthreads();
    }
    if (threadIdx.x == 0) {
        int pos = ri[0];
        colsum[j] = 1;
        int old = atomicAdd(&rowcnt[pos], 1);
        if (old >= 1) scal[S_MULTI] = 1;   // same-iteration collision
        atomicMin(&rowfirst[pos], j);
        atomicMin(&rowiter[pos], t);       // matched at iteration t
    }
}

// ---------------------------------------------------------------------------
// iterC (m_fix): iff body ran at t && anymulti: each prior row re-argmins its
// inflated cost (exact sequential +1e5 per elapsed iteration).
// ---------------------------------------------------------------------------
__global__ __launch_bounds__(256) void k_iterC(const float* __restrict__ pb,
        const float* __restrict__ gb, const int* __restrict__ glab,
        const float* __restrict__ clsval,
        const float4* __restrict__ pnorm, const float4* __restrict__ pinfo,
        const float4* __restrict__ gcb, const float4* __restrict__ gnm,
        const float* __restrict__ gar,
        const int* __restrict__ plist, const int* __restrict__ rowiter,
        int* __restrict__ priorcol, int* __restrict__ colsum,
        int* __restrict__ scal, int t)
{
    if (scal[S_BODY + t] == 0 || scal[S_MULTI] == 0) return;
    if ((int)blockIdx.x >= scal[S_NPRI]) return;
    int row = plist[blockIdx.x];
    int k = t - rowiter[row]; if (k < 0) k = 0;
    float4 p = ((const float4*)pb)[row];
    float4 pn = pnorm[row];
    float4 pi4 = pinfo[row];

    __shared__ float rv[256]; __shared__ int ri[256];
    float best = FLT_MAX; int bj = 0x7fffffff;
    for (int j = threadIdx.x; j < NG; j += 256) {
        float cc, iou;
        cost_iou(p, pn, pi4, ((const float4*)gb)[j], gcb[j], gnm[j], gar[j],
                 clsval[(size_t)glab[j] * NP + row], cc, iou);
        float val = inflate(cc, k);
        if (lexless(val, j, best, bj)) { best = val; bj = j; }
    }
    rv[threadIdx.x] = best; ri[threadIdx.x] = bj; __syncthreads();
    for (int w = 128; w > 0; w >>= 1) {
        if (threadIdx.x < (unsigned)w) {
            float ov = rv[threadIdx.x + w]; int oi = ri[threadIdx.x + w];
            if (lexless(ov, oi, rv[threadIdx.x], ri[threadIdx.x])) {
                rv[threadIdx.x] = ov; ri[threadIdx.x] = oi;
            }
        }
        __syncthreads();
    }
    if (threadIdx.x == 0) {
        int nb = ri[0];
        int oldc = priorcol[row];
        if (nb != oldc) {
            atomicSub(&colsum[oldc], 1);
            atomicAdd(&colsum[nb], 1);
            priorcol[row] = nb;
        }
    }
}

// ---------------------------------------------------------------------------
// Final: fg = rowcnt>0; matched = priorcol (prior rows) else rowfirst. int32.
// ---------------------------------------------------------------------------
__global__ __launch_bounds__(256) void k_final(const int* __restrict__ rowcnt,
        const int* __restrict__ prior, const int* __restrict__ priorcol,
        const int* __restrict__ rowfirst, int* __restrict__ out)
{
    int i = blockIdx.x * 256 + threadIdx.x;
    if (i >= NP) return;
    int fg = rowcnt[i] > 0;
    out[i] = fg ? 1 : 0;
    out[NP + i] = fg ? (prior[i] ? priorcol[i] : rowfirst[i]) : 0;
}

extern "C" void kernel_launch(void* const* d_in, const int* in_sizes, int n_in,
                              void* d_out, int out_size, void* d_ws, size_t ws_size,
                              hipStream_t stream)
{
    (void)in_sizes; (void)n_in; (void)out_size; (void)ws_size;
    const float* logits = (const float*)d_in[0];
    const float* pboxes = (const float*)d_in[1];
    const float* gboxes = (const float*)d_in[2];
    const int*   glab   = (const int*)d_in[3];
    const int*   imgh   = (const int*)d_in[4];
    const int*   imgw   = (const int*)d_in[5];
    int* out = (int*)d_out;

    char* w = (char*)d_ws;
    float*  clsval  = (float*)(w);                    // 3,200,000
    float4* pnorm   = (float4*)(w + 3200000);         //   160,000
    float4* pinfo   = (float4*)(w + 3360000);         //   160,000
    float4* gcb     = (float4*)(w + 3520000);         //    16,000
    float4* gnm     = (float4*)(w + 3536000);         //    16,000
    float*  gar     = (float*)(w + 3552000);          //     4,000
    int* rowcnt     = (int*)(w + 3556000);            //    40,000
    int* rowfirst   = (int*)(w + 3596000);            //    40,000
    int* rowiter    = (int*)(w + 3636000);            //    40,000
    int* prior      = (int*)(w + 3676000);            //    40,000
    int* priorcol   = (int*)(w + 3716000);            //    40,000
    int* plist      = (int*)(w + 3756000);            //    40,000
    int* picks      = (int*)(w + 3796000);            //    20,000
    int* dkarr      = (int*)(w + 3816000);            //     4,000
    int* colsum     = (int*)(w + 3820000);            //     4,000
    int* scal       = (int*)(w + 3824000);            //       128
    float* pcv      = (float*)(w + 3824128);          //    80,000
    int*   pci      = (int*)(w + 3904128);            //    80,000
    float* piv      = (float*)(w + 3984128);          //    80,000

    hipLaunchKernelGGL(k_prep, dim3(2701), dim3(256), 0, stream,
                       logits, pboxes, gboxes, imgw, imgh,
                       clsval, pnorm, pinfo, gcb, gnm, gar,
                       rowcnt, rowfirst, rowiter, prior, priorcol, colsum, scal);
    hipLaunchKernelGGL(k_cost4, dim3(NG * NCH), dim3(256), 0, stream,
                       pboxes, gboxes, glab, clsval, pnorm, pinfo, gcb, gnm, gar,
                       pcv, pci, piv);
    hipLaunchKernelGGL(k_costmerge, dim3(4), dim3(256), 0, stream,
                       pcv, pci, piv, rowcnt, rowfirst, rowiter, picks, dkarr);
    hipLaunchKernelGGL(k_pscan, dim3(40), dim3(256), 0, stream,
                       rowcnt, prior, plist, scal);
    hipLaunchKernelGGL(k_pfixsurv, dim3(2504), dim3(256), 0, stream,
                       pboxes, gboxes, glab, clsval, pnorm, pinfo, gcb, gnm, gar,
                       plist, priorcol, colsum, scal, rowcnt, picks, dkarr);
    for (int t = 0; t < LMAX; t++) {
        hipLaunchKernelGGL(k_iterB, dim3(NG), dim3(256), 0, stream,
                           pboxes, gboxes, glab, clsval, pnorm, pinfo, gcb, gnm, gar,
                           rowiter, rowcnt, rowfirst, colsum, scal, t);
        hipLaunchKernelGGL(k_iterC, dim3(2500), dim3(256), 0, stream,
                           pboxes, gboxes, glab, clsval, pnorm, pinfo, gcb, gnm, gar,
                           plist, rowiter, priorcol, colsum, scal, t);
    }
    hipLaunchKernelGGL(k_final, dim3(40), dim3(256), 0, stream,
                       rowcnt, prior, priorcol, rowfirst, out);
}